// Round 6
// baseline (1618.349 us; speedup 1.0000x reference)
//
#include <hip/hip_runtime.h>

// GlobalNet conv-GRU on MI355X — round 11.
// r10 post-mortem: launch_bounds(640,3) on the r5 shape was NEUTRAL (1281us) —
// at 10 waves/CU, TLP already hides codegen slop; the binding term is each CU
// re-streaming the full 1.05MB packed-B from L2 every step (~7.8us of 19.4).
// B bytes scale as 1/M_w. r6 (M_w=64, 320thr) tested that lever but compiled
// at the 84-VGPR heuristic (r7/r9 evidence) -> rolling prefetch in scratch ->
// its 1618us measured the SPILL, not the structure. THIS round: r6 source
// byte-for-byte + __launch_bounds__(320, 2) -> 256-VGPR budget, ~186 live regs
// resident, zero scratch. Occupancy 5 waves/CU (2/1/1/1): latency hiding moves
// from TLP to the 3-deep B prefetch ILP. Numerics identical to r6/r5: absmax
// must be exactly 0.004272461.

#define Bn   16
#define Tn   64
#define Ln   512
#define Cn   64
#define Hn   150
#define G3   450
#define SW   160
#define HP   160    // padded hidden
#define KCH  25     // k-chunks (32) for h GEMM (K=800)
#define KCX  10     // k-chunks for x GEMM (K=320)
#define Mtot 8192   // Bn*Ln
#define NTH  320    // 5 waves per block

typedef __bf16 bf16x8 __attribute__((ext_vector_type(8)));
typedef float  f32x4  __attribute__((ext_vector_type(4)));
typedef short  s16x4  __attribute__((ext_vector_type(4)));

__device__ inline short f2bf(float f) {
  unsigned u = __builtin_bit_cast(unsigned, f);
  u += 0x7fffu + ((u >> 16) & 1u);   // RNE (finite inputs)
  return (short)(u >> 16);
}

// Packed B layout: [nt (n/16)][kc][lane (quad*16+l16)][j (8)] shorts.
// Fragment element: B[k = kc*32+quad*8+j][n = nt*16+l16].
// n maps (seg=n/160, jl=n%160) -> orig col seg*150+jl (zero pad elsewhere).
__global__ __launch_bounds__(256) void pack_weights(const float* __restrict__ ki,
                                                    const float* __restrict__ kh,
                                                    short* __restrict__ Bx,
                                                    short* __restrict__ Bh) {
  int idx = blockIdx.x * 256 + threadIdx.x;
  if (idx < 32 * KCH * 512) {
    int j = idx & 7, lane = (idx >> 3) & 63;
    int rest = idx >> 9;
    int kc = rest % KCH, nt = rest / KCH;
    int quad = lane >> 4, l16 = lane & 15;
    int n = nt * 16 + l16, seg = n / SW, jl = n - seg * SW;
    int kk = kc / 5, jj = (kc - kk * 5) * 32 + quad * 8 + j;
    float v = (seg < 3 && jl < Hn && jj < Hn) ? kh[(kk * Hn + jj) * G3 + seg * Hn + jl] : 0.f;
    Bh[idx] = f2bf(v);
  } else {
    int r = idx - 32 * KCH * 512;
    if (r < 32 * KCX * 512) {
      int j = r & 7, lane = (r >> 3) & 63;
      int rest = r >> 9;
      int kc = rest % KCX, nt = rest / KCX;
      int quad = lane >> 4, l16 = lane & 15;
      int n = nt * 16 + l16, seg = n / SW, jl = n - seg * SW;
      int kk = kc / 2, cc = (kc - kk * 2) * 32 + quad * 8 + j;
      float v = (seg < 3 && jl < Hn) ? ki[(kk * Cn + cc) * G3 + seg * Hn + jl] : 0.f;
      Bx[r] = f2bf(v);
    }
  }
}

// One recurrent step, M=64 rows per wave (halves per-CU B-from-L2 stream).
// Grid 256 blocks x 320 threads (5 waves): blockIdx = mb*2 + ns.
// mb -> (bb = mb/8, l0 = (mb%8)*64); ns selects j-half [0,80) / [80,160).
// Wave w owns n-tiles {ns*5+w+10g} for g = r/z/n, rows l0..l0+63 (4 m-frags).
// launch_bounds(320,2): VGPR budget 256 -> acc[4][3]+axn[4] (64) + bh[4][3]
// (48) + bx[3][3] (36) + frags/ptrs stay in registers (r6 ran this at 84 and
// spilled everything to scratch).
__global__ __launch_bounds__(NTH, 2)
void gru_step(const short* __restrict__ hbin, short* __restrict__ hbout,
              float* __restrict__ hf, const short* __restrict__ Bh,
              const short* __restrict__ Bx, const float* __restrict__ xs, int t) {
  __shared__ short awh[68 * 168];   // h window rows l0-2..l0+65, 160 ch (22.8 KB)
  __shared__ short awx[68 * 72];    // x window, 64 ch (9.8 KB)
  const int tid = threadIdx.x;
  const int ns  = blockIdx.x & 1;
  const int mb  = blockIdx.x >> 1;
  const int bb  = mb >> 3;
  const int l0  = (mb & 7) << 6;

  // Batched staging: issue ALL global loads first (latency overlapped), then
  // convert/write to LDS. h: 68 rows x 40 s16x4 = 2720 items (9 rounds).
  // x: 68 rows x 16 f32x4 = 1088 items (4 rounds).
  {
    s16x4 th[9];
#pragma unroll
    for (int u = 0; u < 9; ++u) {
      int i = tid + u * NTH;
      int r = i / 40, c4 = (i - r * 40) * 4;
      int l = l0 - 2 + r;
      s16x4 v = {0, 0, 0, 0};
      if (i < 2720 && l >= 0 && l < Ln)
        v = *(const s16x4*)&hbin[((size_t)bb * Ln + l) * HP + c4];
      th[u] = v;
    }
    f32x4 tx[4];
#pragma unroll
    for (int u = 0; u < 4; ++u) {
      int i = tid + u * NTH;
      int r = i >> 4, c4 = (i & 15) * 4;
      int l = l0 - 2 + r;
      f32x4 f = {0.f, 0.f, 0.f, 0.f};
      if (i < 1088 && l >= 0 && l < Ln)
        f = *(const f32x4*)&xs[(((size_t)bb * Tn + t) * Ln + l) * Cn + c4];
      tx[u] = f;
    }
#pragma unroll
    for (int u = 0; u < 9; ++u) {
      int i = tid + u * NTH;
      if (i < 2720) {
        int r = i / 40, c4 = (i - r * 40) * 4;
        *(s16x4*)&awh[r * 168 + c4] = th[u];
      }
    }
#pragma unroll
    for (int u = 0; u < 4; ++u) {
      int i = tid + u * NTH;
      if (i < 1088) {
        int r = i >> 4, c4 = (i & 15) * 4;
        s16x4 v;
        v[0] = f2bf(tx[u][0]); v[1] = f2bf(tx[u][1]);
        v[2] = f2bf(tx[u][2]); v[3] = f2bf(tx[u][3]);
        *(s16x4*)&awx[r * 72 + c4] = v;
      }
    }
  }
  __syncthreads();

  const int lane = tid & 63, w = tid >> 6;   // w in [0,5)
  const int quad = lane >> 4, l16 = lane & 15;

  const short* Bph[3];
  const short* Bpx[3];
#pragma unroll
  for (int g = 0; g < 3; ++g) {
    const int nt = ns * 5 + w + 10 * g;
    Bph[g] = Bh + (size_t)nt * (KCH * 512) + lane * 8;
    Bpx[g] = Bx + (size_t)nt * (KCX * 512) + lane * 8;
  }
  const int arh = l16 * 168 + quad * 8;
  const int arx = l16 * 72 + quad * 8;

  f32x4 acc[4][3] = {};   // r | z | n(h-part), 4 m-frags
  f32x4 axn[4] = {};      // n(x-part): n = tanh(iin + r*hin)

  bf16x8 bh[4][3];   // 4-stage rolling prefetch (3 ahead ~ 300-450 cyc cover)
  bf16x8 bx[3][3];
#pragma unroll
  for (int s = 0; s < 3; ++s)
#pragma unroll
    for (int g = 0; g < 3; ++g) bh[s][g] = *(const bf16x8*)(Bph[g] + s * 512);

#pragma unroll
  for (int kc = 0; kc < KCH; ++kc) {
    const int cur = kc & 3;
    if (kc + 3 < KCH) {
      const int nxt = (kc + 3) & 3;
#pragma unroll
      for (int g = 0; g < 3; ++g)
        bh[nxt][g] = *(const bf16x8*)(Bph[g] + (kc + 3) * 512);
    }
    if (kc == KCH - 3) {   // prime x-phase B loads late (deep in flight)
#pragma unroll
      for (int g = 0; g < 3; ++g) bx[0][g] = *(const bf16x8*)(Bpx[g]);
    }
    if (kc == KCH - 2) {
#pragma unroll
      for (int g = 0; g < 3; ++g) bx[1][g] = *(const bf16x8*)(Bpx[g] + 512);
    }
    const int kk = kc / 5, jj = (kc - kk * 5) * 32;
    const short* ar = &awh[arh + kk * 168 + jj];
    bf16x8 a0 = *(const bf16x8*)(ar);
    bf16x8 a1 = *(const bf16x8*)(ar + 16 * 168);
    bf16x8 a2 = *(const bf16x8*)(ar + 32 * 168);
    bf16x8 a3 = *(const bf16x8*)(ar + 48 * 168);
#pragma unroll
    for (int g = 0; g < 3; ++g) {
      acc[0][g] = __builtin_amdgcn_mfma_f32_16x16x32_bf16(a0, bh[cur][g], acc[0][g], 0, 0, 0);
      acc[1][g] = __builtin_amdgcn_mfma_f32_16x16x32_bf16(a1, bh[cur][g], acc[1][g], 0, 0, 0);
      acc[2][g] = __builtin_amdgcn_mfma_f32_16x16x32_bf16(a2, bh[cur][g], acc[2][g], 0, 0, 0);
      acc[3][g] = __builtin_amdgcn_mfma_f32_16x16x32_bf16(a3, bh[cur][g], acc[3][g], 0, 0, 0);
    }
  }

#pragma unroll
  for (int kc = 0; kc < KCX; ++kc) {
    const int cur = kc % 3;
    if (kc + 2 < KCX) {
      const int nxt = (kc + 2) % 3;
#pragma unroll
      for (int g = 0; g < 3; ++g)
        bx[nxt][g] = *(const bf16x8*)(Bpx[g] + (kc + 2) * 512);
    }
    const int kk = kc >> 1, jj = (kc & 1) * 32;
    const short* ar = &awx[arx + kk * 72 + jj];
    bf16x8 a0 = *(const bf16x8*)(ar);
    bf16x8 a1 = *(const bf16x8*)(ar + 16 * 72);
    bf16x8 a2 = *(const bf16x8*)(ar + 32 * 72);
    bf16x8 a3 = *(const bf16x8*)(ar + 48 * 72);
#pragma unroll
    for (int mi = 0; mi < 4; ++mi) {
      const bf16x8 am = (mi == 0) ? a0 : (mi == 1) ? a1 : (mi == 2) ? a2 : a3;
      acc[mi][0] = __builtin_amdgcn_mfma_f32_16x16x32_bf16(am, bx[cur][0], acc[mi][0], 0, 0, 0);
      acc[mi][1] = __builtin_amdgcn_mfma_f32_16x16x32_bf16(am, bx[cur][1], acc[mi][1], 0, 0, 0);
      axn[mi]    = __builtin_amdgcn_mfma_f32_16x16x32_bf16(am, bx[cur][2], axn[mi], 0, 0, 0);
    }
  }

  // Gates: lane covers j = ns*80 + w*16 + l16, rows ml = mi*16 + quad*4 + r.
  const int j = ns * 80 + w * 16 + l16;
  if (j < Hn) {
    const size_t mrow0 = (size_t)bb * Ln + l0;
    float hold[4][4];
#pragma unroll
    for (int mi = 0; mi < 4; ++mi)
#pragma unroll
      for (int r = 0; r < 4; ++r) {
        const int ml = mi * 16 + quad * 4 + r;
        hold[mi][r] = hf[(mrow0 + ml) * Hn + j];   // hoisted: one load burst
      }
#pragma unroll
    for (int mi = 0; mi < 4; ++mi)
#pragma unroll
      for (int r = 0; r < 4; ++r) {
        const int ml = mi * 16 + quad * 4 + r;
        const size_t mrow = mrow0 + ml;
        float rg = 1.f / (1.f + __expf(-acc[mi][0][r]));
        float zg = 1.f / (1.f + __expf(-acc[mi][1][r]));
        float xg = axn[mi][r] + rg * acc[mi][2][r];
        xg = fminf(fmaxf(xg, -15.f), 15.f);
        float e = __expf(2.f * xg);
        float n = (e - 1.f) / (e + 1.f);
        float hn = (1.f - zg) * n + zg * hold[mi][r];
        hf[mrow * Hn + j] = hn;
        hbout[mrow * HP + j] = f2bf(hn);
      }
  }
}

// Head: thread-per-output fp32.
__global__ __launch_bounds__(256) void head1(const float* __restrict__ hf,
                                             const float* __restrict__ W1,
                                             const float* __restrict__ b1,
                                             float* __restrict__ hdn) {
  int idx = blockIdx.x * 256 + threadIdx.x;
  if (idx >= Mtot * Hn) return;
  int m = idx / Hn, j = idx - m * Hn;
  const float* hr = hf + (size_t)m * Hn;
  float acc = b1[j];
#pragma unroll 10
  for (int i = 0; i < Hn; ++i) acc = fmaf(hr[i], W1[i * Hn + j], acc);
  hdn[idx] = acc / (1.f + __expf(-acc));   // silu
}
__global__ __launch_bounds__(256) void head2(const float* __restrict__ hdn,
                                             const float* __restrict__ W2,
                                             const float* __restrict__ b2,
                                             float* __restrict__ out) {
  int idx = blockIdx.x * 256 + threadIdx.x;
  if (idx >= Mtot * 24) return;
  int m = idx / 24, j = idx - m * 24;
  const float* hr = hdn + (size_t)m * Hn;
  float acc = b2[j];
#pragma unroll 10
  for (int i = 0; i < Hn; ++i) acc = fmaf(hr[i], W2[i * 24 + j], acc);
  out[idx] = acc;
}

extern "C" void kernel_launch(void* const* d_in, const int* in_sizes, int n_in,
                              void* d_out, int out_size, void* d_ws, size_t ws_size,
                              hipStream_t stream) {
  const float* xs = (const float*)d_in[0];
  const float* ki = (const float*)d_in[1];
  const float* kh = (const float*)d_in[2];
  const float* W1 = (const float*)d_in[3];
  const float* b1 = (const float*)d_in[4];
  const float* W2 = (const float*)d_in[5];
  const float* b2 = (const float*)d_in[6];
  float* out = (float*)d_out;

  char* p = (char*)d_ws;
  float* hf  = (float*)p; p += (size_t)Mtot * Hn * 4;       // 4.7 MiB
  float* hdn = (float*)p; p += (size_t)Mtot * Hn * 4;       // 4.7 MiB
  short* hbA = (short*)p; p += (size_t)Mtot * HP * 2;       // 2.5 MiB
  short* hbB = (short*)p; p += (size_t)Mtot * HP * 2;       // 2.5 MiB
  short* Bh  = (short*)p; p += (size_t)32 * KCH * 512 * 2;  // 0.8 MiB
  short* Bx  = (short*)p; p += (size_t)32 * KCX * 512 * 2;  // 0.3 MiB

  hipMemsetAsync(hf, 0, (size_t)Mtot * Hn * 4, stream);
  hipMemsetAsync(hbA, 0, (size_t)Mtot * HP * 2 * 2, stream);  // both buffers; pads stay 0
  pack_weights<<<(32 * (KCH + KCX) * 512 + 255) / 256, 256, 0, stream>>>(ki, kh, Bx, Bh);

  for (int t = 0; t < Tn; ++t) {
    short* hin  = (t & 1) ? hbB : hbA;
    short* hout = (t & 1) ? hbA : hbB;
    gru_step<<<256, NTH, 0, stream>>>(hin, hout, hf, Bh, Bx, xs, t);
  }
  head1<<<(Mtot * Hn + 255) / 256, 256, 0, stream>>>(hf, W1, b1, hdn);
  head2<<<(Mtot * 24 + 255) / 256, 256, 0, stream>>>(hdn, W2, b2, out);
}

// Round 7
// 1410.959 us; speedup vs baseline: 1.1470x; 1.1470x over previous
//
#include <hip/hip_runtime.h>

// GlobalNet conv-GRU on MI355X — round 12.
// r11 post-mortem: LB(320,2) was EXACTLY neutral vs r6 (1618us both) ->
// register budget irrelevant; B-from-L2 was never BW-bound either
// (275MB/step / 19.4us = 14 TB/s << 34.5 L2 ceiling; 54 GB/s/CU << 135).
// Step-time ranking r5(10w/CU)=19.4 < r8=22 < r6/r11(5w/CU)=24.5 us tracks
// WAVES and SERIAL BUBBLES (launch gap, staging latency, barrier, drain),
// not B bytes: at 1 block/CU nothing overlaps the bubbles. THIS round:
// same r5 wave-work, but 512 blocks x 320 thr (5 waves) = 2 blocks/CU.
// Block (mb, ns) = 32-row window x N-half; co-resident twin blocks overlap
// each other's staging/epilogue bubbles. Inner loops verbatim r5/r10.
// LB(320,3) -> 170 VGPR, 3 waves/SIMD, 2 blocks/CU fit (LDS 2x17.3KB).
// Numerics bit-identical: absmax must be exactly 0.004272461.

#define Bn   16
#define Tn   64
#define Ln   512
#define Cn   64
#define Hn   150
#define G3   450
#define SW   160
#define HP   160    // padded hidden
#define KCH  25     // k-chunks (32) for h GEMM (K=800)
#define KCX  10     // k-chunks for x GEMM (K=320)
#define Mtot 8192   // Bn*Ln
#define NTH  320    // 5 waves per block

typedef __bf16 bf16x8 __attribute__((ext_vector_type(8)));
typedef float  f32x4  __attribute__((ext_vector_type(4)));
typedef short  s16x4  __attribute__((ext_vector_type(4)));

__device__ inline short f2bf(float f) {
  unsigned u = __builtin_bit_cast(unsigned, f);
  u += 0x7fffu + ((u >> 16) & 1u);   // RNE (finite inputs)
  return (short)(u >> 16);
}

// Packed B layout: [nt (n/16)][kc][lane (quad*16+l16)][j (8)] shorts.
// Fragment element: B[k = kc*32+quad*8+j][n = nt*16+l16].
// n maps (seg=n/160, jl=n%160) -> orig col seg*150+jl (zero pad elsewhere).
__global__ __launch_bounds__(256) void pack_weights(const float* __restrict__ ki,
                                                    const float* __restrict__ kh,
                                                    short* __restrict__ Bx,
                                                    short* __restrict__ Bh) {
  int idx = blockIdx.x * 256 + threadIdx.x;
  if (idx < 32 * KCH * 512) {
    int j = idx & 7, lane = (idx >> 3) & 63;
    int rest = idx >> 9;
    int kc = rest % KCH, nt = rest / KCH;
    int quad = lane >> 4, l16 = lane & 15;
    int n = nt * 16 + l16, seg = n / SW, jl = n - seg * SW;
    int kk = kc / 5, jj = (kc - kk * 5) * 32 + quad * 8 + j;
    float v = (seg < 3 && jl < Hn && jj < Hn) ? kh[(kk * Hn + jj) * G3 + seg * Hn + jl] : 0.f;
    Bh[idx] = f2bf(v);
  } else {
    int r = idx - 32 * KCH * 512;
    if (r < 32 * KCX * 512) {
      int j = r & 7, lane = (r >> 3) & 63;
      int rest = r >> 9;
      int kc = rest % KCX, nt = rest / KCX;
      int quad = lane >> 4, l16 = lane & 15;
      int n = nt * 16 + l16, seg = n / SW, jl = n - seg * SW;
      int kk = kc / 2, cc = (kc - kk * 2) * 32 + quad * 8 + j;
      float v = (seg < 3 && jl < Hn) ? ki[(kk * Cn + cc) * G3 + seg * Hn + jl] : 0.f;
      Bx[r] = f2bf(v);
    }
  }
}

// One recurrent step. Grid 512 = 256 m-blocks (bb = mb/16, l0 = (mb%16)*32,
// 32 rows) x 2 N-halves (ns). 320 threads (5 waves): wave w owns n-tiles
// {ns*5+w+10g} for g = r/z/n gates, j in [ns*80+16w, ns*80+16w+16).
// 2 blocks/CU: twin blocks overlap each other's staging/epilogue bubbles.
__global__ __launch_bounds__(NTH, 3)
void gru_step(const short* __restrict__ hbin, short* __restrict__ hbout,
              float* __restrict__ hf, const short* __restrict__ Bh,
              const short* __restrict__ Bx, const float* __restrict__ xs, int t) {
  __shared__ short awh[36 * 168];   // h window rows l0-2..l0+33, 160 ch (12.1 KB)
  __shared__ short awx[36 * 72];    // x window, 64 ch (5.2 KB)
  const int tid = threadIdx.x;
  const int ns  = blockIdx.x & 1;
  const int mb  = blockIdx.x >> 1;
  const int bb  = mb >> 4;
  const int l0  = (mb & 15) << 5;

  for (int i = tid; i < 36 * 40; i += NTH) {
    int r = i / 40, c4 = (i - r * 40) * 4;
    int l = l0 - 2 + r;
    s16x4 v = {0, 0, 0, 0};
    if (l >= 0 && l < Ln) v = *(const s16x4*)&hbin[((size_t)bb * Ln + l) * HP + c4];
    *(s16x4*)&awh[r * 168 + c4] = v;
  }
  for (int i = tid; i < 36 * 16; i += NTH) {
    int r = i >> 4, c4 = (i & 15) * 4;
    int l = l0 - 2 + r;
    s16x4 v = {0, 0, 0, 0};
    if (l >= 0 && l < Ln) {
      f32x4 f = *(const f32x4*)&xs[(((size_t)bb * Tn + t) * Ln + l) * Cn + c4];
      v[0] = f2bf(f[0]); v[1] = f2bf(f[1]); v[2] = f2bf(f[2]); v[3] = f2bf(f[3]);
    }
    *(s16x4*)&awx[r * 72 + c4] = v;
  }
  __syncthreads();

  const int lane = tid & 63, w = tid >> 6;   // w in [0,5)
  const int quad = lane >> 4, l16 = lane & 15;

  const short* Bph[3];
  const short* Bpx[3];
#pragma unroll
  for (int g = 0; g < 3; ++g) {
    const int nt = ns * 5 + w + 10 * g;
    Bph[g] = Bh + (size_t)nt * (KCH * 512) + lane * 8;
    Bpx[g] = Bx + (size_t)nt * (KCX * 512) + lane * 8;
  }
  const int arh = l16 * 168 + quad * 8;
  const int arx = l16 * 72 + quad * 8;

  f32x4 acc[2][3] = {};   // r | z | n(h-part)
  f32x4 axn[2] = {};      // n(x-part), kept separate: n = tanh(iin + r*hin)

  // Prime x-phase B loads early (independent of the h loop — deep in flight).
  bf16x8 bx[3][3];
#pragma unroll
  for (int s = 0; s < 2; ++s)
#pragma unroll
    for (int g = 0; g < 3; ++g) bx[s][g] = *(const bf16x8*)(Bpx[g] + s * 512);

  bf16x8 bh[4][3];   // 4-stage rolling prefetch
#pragma unroll
  for (int s = 0; s < 3; ++s)
#pragma unroll
    for (int g = 0; g < 3; ++g) bh[s][g] = *(const bf16x8*)(Bph[g] + s * 512);

#pragma unroll
  for (int kc = 0; kc < KCH; ++kc) {
    const int cur = kc & 3;
    if (kc + 3 < KCH) {
      const int nxt = (kc + 3) & 3;
#pragma unroll
      for (int g = 0; g < 3; ++g)
        bh[nxt][g] = *(const bf16x8*)(Bph[g] + (kc + 3) * 512);
    }
    const int kk = kc / 5, jj = (kc - kk * 5) * 32;
    const short* ar = &awh[arh + kk * 168 + jj];
    bf16x8 a0 = *(const bf16x8*)(ar);
    bf16x8 a1 = *(const bf16x8*)(ar + 16 * 168);
#pragma unroll
    for (int g = 0; g < 3; ++g) {
      acc[0][g] = __builtin_amdgcn_mfma_f32_16x16x32_bf16(a0, bh[cur][g], acc[0][g], 0, 0, 0);
      acc[1][g] = __builtin_amdgcn_mfma_f32_16x16x32_bf16(a1, bh[cur][g], acc[1][g], 0, 0, 0);
    }
  }

#pragma unroll
  for (int kc = 0; kc < KCX; ++kc) {
    const int cur = kc % 3;
    if (kc + 2 < KCX) {
      const int nxt = (kc + 2) % 3;
#pragma unroll
      for (int g = 0; g < 3; ++g)
        bx[nxt][g] = *(const bf16x8*)(Bpx[g] + (kc + 2) * 512);
    }
    const int kk = kc >> 1, jj = (kc & 1) * 32;
    const short* ar = &awx[arx + kk * 72 + jj];
    bf16x8 a0 = *(const bf16x8*)(ar);
    bf16x8 a1 = *(const bf16x8*)(ar + 16 * 72);
    acc[0][0] = __builtin_amdgcn_mfma_f32_16x16x32_bf16(a0, bx[cur][0], acc[0][0], 0, 0, 0);
    acc[1][0] = __builtin_amdgcn_mfma_f32_16x16x32_bf16(a1, bx[cur][0], acc[1][0], 0, 0, 0);
    acc[0][1] = __builtin_amdgcn_mfma_f32_16x16x32_bf16(a0, bx[cur][1], acc[0][1], 0, 0, 0);
    acc[1][1] = __builtin_amdgcn_mfma_f32_16x16x32_bf16(a1, bx[cur][1], acc[1][1], 0, 0, 0);
    axn[0]    = __builtin_amdgcn_mfma_f32_16x16x32_bf16(a0, bx[cur][2], axn[0], 0, 0, 0);
    axn[1]    = __builtin_amdgcn_mfma_f32_16x16x32_bf16(a1, bx[cur][2], axn[1], 0, 0, 0);
  }

  // Gates: lane covers j = ns*80 + w*16 + l16, m-rows mi*16 + quad*4 + r.
  const int j = ns * 80 + w * 16 + l16;
  if (j < Hn) {
#pragma unroll
    for (int mi = 0; mi < 2; ++mi)
#pragma unroll
      for (int r = 0; r < 4; ++r) {
        const int ml = mi * 16 + quad * 4 + r;
        const size_t mrow = (size_t)bb * Ln + l0 + ml;
        float rg = 1.f / (1.f + __expf(-acc[mi][0][r]));
        float zg = 1.f / (1.f + __expf(-acc[mi][1][r]));
        float xg = axn[mi][r] + rg * acc[mi][2][r];
        xg = fminf(fmaxf(xg, -15.f), 15.f);
        float e = __expf(2.f * xg);
        float n = (e - 1.f) / (e + 1.f);
        float hn = (1.f - zg) * n + zg * hf[mrow * Hn + j];
        hf[mrow * Hn + j] = hn;
        hbout[mrow * HP + j] = f2bf(hn);
      }
  }
}

// Head: thread-per-output fp32.
__global__ __launch_bounds__(256) void head1(const float* __restrict__ hf,
                                             const float* __restrict__ W1,
                                             const float* __restrict__ b1,
                                             float* __restrict__ hdn) {
  int idx = blockIdx.x * 256 + threadIdx.x;
  if (idx >= Mtot * Hn) return;
  int m = idx / Hn, j = idx - m * Hn;
  const float* hr = hf + (size_t)m * Hn;
  float acc = b1[j];
#pragma unroll 10
  for (int i = 0; i < Hn; ++i) acc = fmaf(hr[i], W1[i * Hn + j], acc);
  hdn[idx] = acc / (1.f + __expf(-acc));   // silu
}
__global__ __launch_bounds__(256) void head2(const float* __restrict__ hdn,
                                             const float* __restrict__ W2,
                                             const float* __restrict__ b2,
                                             float* __restrict__ out) {
  int idx = blockIdx.x * 256 + threadIdx.x;
  if (idx >= Mtot * 24) return;
  int m = idx / 24, j = idx - m * 24;
  const float* hr = hdn + (size_t)m * Hn;
  float acc = b2[j];
#pragma unroll 10
  for (int i = 0; i < Hn; ++i) acc = fmaf(hr[i], W2[i * 24 + j], acc);
  out[idx] = acc;
}

extern "C" void kernel_launch(void* const* d_in, const int* in_sizes, int n_in,
                              void* d_out, int out_size, void* d_ws, size_t ws_size,
                              hipStream_t stream) {
  const float* xs = (const float*)d_in[0];
  const float* ki = (const float*)d_in[1];
  const float* kh = (const float*)d_in[2];
  const float* W1 = (const float*)d_in[3];
  const float* b1 = (const float*)d_in[4];
  const float* W2 = (const float*)d_in[5];
  const float* b2 = (const float*)d_in[6];
  float* out = (float*)d_out;

  char* p = (char*)d_ws;
  float* hf  = (float*)p; p += (size_t)Mtot * Hn * 4;       // 4.7 MiB
  float* hdn = (float*)p; p += (size_t)Mtot * Hn * 4;       // 4.7 MiB
  short* hbA = (short*)p; p += (size_t)Mtot * HP * 2;       // 2.5 MiB
  short* hbB = (short*)p; p += (size_t)Mtot * HP * 2;       // 2.5 MiB
  short* Bh  = (short*)p; p += (size_t)32 * KCH * 512 * 2;  // 0.8 MiB
  short* Bx  = (short*)p; p += (size_t)32 * KCX * 512 * 2;  // 0.3 MiB

  hipMemsetAsync(hf, 0, (size_t)Mtot * Hn * 4, stream);
  hipMemsetAsync(hbA, 0, (size_t)Mtot * HP * 2 * 2, stream);  // both buffers; pads stay 0
  pack_weights<<<(32 * (KCH + KCX) * 512 + 255) / 256, 256, 0, stream>>>(ki, kh, Bx, Bh);

  for (int t = 0; t < Tn; ++t) {
    short* hin  = (t & 1) ? hbB : hbA;
    short* hout = (t & 1) ? hbA : hbB;
    gru_step<<<512, NTH, 0, stream>>>(hin, hout, hf, Bh, Bx, xs, t);
  }
  head1<<<(Mtot * Hn + 255) / 256, 256, 0, stream>>>(hf, W1, b1, hdn);
  head2<<<(Mtot * 24 + 255) / 256, 256, 0, stream>>>(hdn, W2, b2, out);
}